// Round 6
// baseline (204.328 us; speedup 1.0000x reference)
//
#include <hip/hip_runtime.h>
#include <math.h>

#define NFFT   2048
#define N1     1024
#define K1     1025
#define KPAD   36
#define MTOT   1097   // K1 + 2*KPAD
#define NFRAMES 1001
#define TLEN   120000
#define BATCH  8
#define FPER   120
#define PIF 3.14159265358979323846f

// LDS swizzle for 8B (float2) elements; balanced for all radix-4 strides and
// the stride-16 brev gathers. Remaining SQ_LDS_BANK_CONFLICT (~1.4e7) is the
// intrinsic multi-cycle cost of 512B/wave b64 ops, not misalignment.
#define A(i) ((i) + ((i) >> 4))      // max 1023 -> 1086; array sized 1088

typedef float2 cpx;
__device__ __forceinline__ cpx cmul(cpx a, cpx b) {
    return make_float2(a.x * b.x - a.y * b.y, a.x * b.y + a.y * b.x);
}
__device__ __forceinline__ cpx cadd(cpx a, cpx b) { return make_float2(a.x + b.x, a.y + b.y); }
__device__ __forceinline__ cpx csub(cpx a, cpx b) { return make_float2(a.x - b.x, a.y - b.y); }

__device__ __forceinline__ int brev10(int v) {
    return (int)(__brev((unsigned)v) >> 22);
}

// ---- fused radix-4 DIF stage (spans H and H/2); w1 = W_{2H}^{tid&(H/2-1)} ----
template<int H>
__device__ __forceinline__ void dif_fused(cpx* c, int tid, cpx w1) {
    int r  = tid & (H / 2 - 1);
    int i0 = (tid / (H / 2)) * (2 * H) + r;
    int ia = A(i0), ib = A(i0 + H / 2), ic = A(i0 + H), id = A(i0 + 3 * H / 2);
    cpx a = c[ia], b = c[ib], cc = c[ic], d = c[id];
    cpx w1n = make_float2(w1.y, -w1.x);                       // -i*w1
    cpx w2  = make_float2(w1.x * w1.x - w1.y * w1.y, 2.0f * w1.x * w1.y);
    cpx a1 = cadd(a, cc);
    cpx c1 = cmul(csub(a, cc), w1);
    cpx b1 = cadd(b, d);
    cpx d1 = cmul(csub(b, d), w1n);
    c[ia] = cadd(a1, b1);
    c[ib] = cmul(csub(a1, b1), w2);
    c[ic] = cadd(c1, d1);
    c[id] = cmul(csub(c1, d1), w2);
    __syncthreads();
}

// last stage (H=2): twiddles are 1 and -i — no multiplies.
__device__ __forceinline__ void dif_last2(cpx* c, int tid) {
    int i0 = 4 * tid;
    int ia = A(i0), ib = A(i0 + 1), ic = A(i0 + 2), id = A(i0 + 3);
    cpx a = c[ia], b = c[ib], cc = c[ic], d = c[id];
    cpx a1 = cadd(a, cc);
    cpx c1 = csub(a, cc);
    cpx b1 = cadd(b, d);
    cpx bd = csub(b, d);
    cpx d1 = make_float2(bd.y, -bd.x);                        // -i*(b-d)
    c[ia] = cadd(a1, b1);
    c[ib] = csub(a1, b1);
    c[ic] = cadd(c1, d1);
    c[id] = csub(c1, d1);
    __syncthreads();
}

__device__ __forceinline__ void fft1024(cpx* c, int tid, const cpx* tw) {
    dif_fused<512>(c, tid, tw[0]);
    dif_fused<128>(c, tid, tw[1]);
    dif_fused<32>(c, tid, tw[2]);
    dif_fused<8>(c, tid, tw[3]);
    dif_last2(c, tid);
}

// Unpack: X[k] = E + w*O, w = W_2048^k (precomputed by caller).
__device__ __forceinline__ cpx unpack_k(const cpx* s_c, int k, cpx w) {
    int kk = k & (N1 - 1);
    int mm = (N1 - kk) & (N1 - 1);
    cpx Zk = s_c[A(brev10(kk))];
    cpx Zm = s_c[A(brev10(mm))];
    float Ex = 0.5f * (Zk.x + Zm.x), Ey = 0.5f * (Zk.y - Zm.y);
    float Ox = 0.5f * (Zk.y + Zm.y), Oy = 0.5f * (Zm.x - Zk.x);
    return make_float2(Ex + w.x * Ox - w.y * Oy,
                       Ey + w.x * Oy + w.y * Ox);
}

// (256,8): needs <=64 VGPR; r5 kernel uses 52 naturally, so no spill expected.
// Spill canary: WRITE_SIZE must stay ~32.3 MB (pure output). If it jumps,
// revert to (256,4) — r4's (256,5/6) bounds spilled at 48/40 VGPR.
__global__ __launch_bounds__(256, 8)
void cheaptrick_kernel(const float* __restrict__ x,
                       const float* __restrict__ f0in,
                       float* __restrict__ out) {
    __shared__ cpx   s_c[1088];
    __shared__ float s_P[1026];
    __shared__ float s_C[MTOT];
    __shared__ float s_scan[16];

    const int tid  = threadIdx.x;
    const int lane = tid & 63;
    const int wid  = tid >> 6;
    const int n    = blockIdx.x;
    const int b    = blockIdx.y;

    float f0 = f0in[b * NFRAMES + n];
    const float F_MIN = 72000.0f / 2045.0f;
    if (f0 <= F_MIN) f0 = 500.0f;

    // ---- frame extraction + raw window (thread-contiguous l = 8t+j) ----
    float fr[8], wn[8];
    float hwl = rintf(36000.0f / f0);
    float s_w2 = 0.0f, s_w = 0.0f, s_fw = 0.0f;
    int base_idx = n * FPER - N1 + 8 * tid;
#pragma unroll
    for (int j = 0; j < 8; ++j) {
        int l = 8 * tid + j;
        float relf = (float)(l - N1);
        int idx = max(0, min(TLEN - 1, base_idx + j));
        fr[j] = x[b * TLEN + idx];
        float w = 0.0f;
        if (fabsf(relf) <= hwl) {
            w = 0.5f * __cosf(PIF * relf / 36000.0f * f0) + 0.5f;
        }
        wn[j] = w;
        s_w2 += w * w;
        s_w  += w;
        s_fw += fr[j] * w;
    }
#pragma unroll
    for (int off = 32; off > 0; off >>= 1) {
        s_w2 += __shfl_down(s_w2, off, 64);
        s_w  += __shfl_down(s_w,  off, 64);
        s_fw += __shfl_down(s_fw, off, 64);
    }
    if (lane == 0) {
        s_scan[wid]     = s_w2;
        s_scan[4 + wid] = s_w;
        s_scan[8 + wid] = s_fw;
    }
    __syncthreads();
    float w2sum = s_scan[0] + s_scan[1] + s_scan[2] + s_scan[3];
    float wsum  = s_scan[4] + s_scan[5] + s_scan[6] + s_scan[7];
    float fwsum = s_scan[8] + s_scan[9] + s_scan[10] + s_scan[11];
    float wscale = 1.0f / sqrtf(w2sum);
    float dc = fwsum / wsum;
    __syncthreads();          // s_scan reuse below

    // ---- FFT1 pack (register-local): z[m] = w[2m] + i*w[2m+1] ----
#pragma unroll
    for (int j = 0; j < 4; ++j) {
        float v0 = wscale * wn[2 * j]     * (fr[2 * j]     - dc);
        float v1 = wscale * wn[2 * j + 1] * (fr[2 * j + 1] - dc);
        s_c[A(4 * tid + j)] = make_float2(v0, v1);
    }

    // ---- twiddle caches (fr/wn now dead; computed once, reused by 3 FFTs) ----
    cpx tw[4], u2048;
    {
        float sn, cs;
        __sincosf(-PIF * (float)(tid & 255) * (1.0f / 512.0f), &sn, &cs);
        tw[0] = make_float2(cs, sn);
        __sincosf(-PIF * (float)(tid & 63) * (1.0f / 128.0f), &sn, &cs);
        tw[1] = make_float2(cs, sn);
        __sincosf(-PIF * (float)(tid & 15) * (1.0f / 32.0f), &sn, &cs);
        tw[2] = make_float2(cs, sn);
        __sincosf(-PIF * (float)(tid & 3) * (1.0f / 8.0f), &sn, &cs);
        tw[3] = make_float2(cs, sn);
        __sincosf(-PIF * (float)tid * (1.0f / 1024.0f), &sn, &cs);
        u2048 = make_float2(cs, sn);          // W_2048^tid
    }
    const float RH = 0.70710678118654752f;
    const cpx W8[5] = { make_float2(1.0f, 0.0f), make_float2(RH, -RH),
                        make_float2(0.0f, -1.0f), make_float2(-RH, -RH),
                        make_float2(-1.0f, 0.0f) };           // W_2048^(256c)

    __syncthreads();
    fft1024(s_c, tid, tw);

    // ---- unpack + power spectrum ----
#pragma unroll
    for (int c5 = 0; c5 < 5; ++c5) {
        int k = tid + (c5 << 8);
        if (k < K1) {
            cpx X = unpack_k(s_c, k, cmul(u2048, W8[c5]));
            s_P[k] = X.x * X.x + X.y * X.y;
        }
    }
    __syncthreads();

    // ---- sub-f0 replacement ----
    float rate = f0 * (2048.0f / 24000.0f);
    int kmax = (int)floorf(rate);
    float repl = 0.0f;
    if (tid <= kmax) {
        float m = rate - (float)tid;
        int lo = (int)floorf(m);
        lo = max(0, min(K1 - 2, lo));
        float frac = m - (float)lo;
        repl = s_P[lo] * (1.0f - frac) + s_P[lo + 1] * frac;
    }
    __syncthreads();
    if (tid <= kmax) s_P[tid] += repl;
    __syncthreads();

    // ---- reflected cumsum: serial-5 + wave shuffle scan ----
    float loc[5];
    float run = 0.0f;
    int basej = tid * 5;
#pragma unroll
    for (int c = 0; c < 5; ++c) {
        int j = basej + c;
        float v = 0.0f;
        if (j < MTOT) {
            int a = abs(j - KPAD);
            if (a > N1) a = NFFT - a;
            v = s_P[a] * (24000.0f / 2048.0f);
        }
        run += v;
        loc[c] = run;
    }
    float v = run;
#pragma unroll
    for (int off = 1; off < 64; off <<= 1) {
        float o = __shfl_up(v, off, 64);
        if (lane >= off) v += o;
    }
    if (lane == 63) s_scan[wid] = v;
    __syncthreads();
    float wbase = 0.0f;
#pragma unroll
    for (int w = 0; w < 4; ++w) wbase += (w < wid) ? s_scan[w] : 0.0f;
    float prefix = wbase + v - run;
#pragma unroll
    for (int c = 0; c < 5; ++c) {
        int j = basej + c;
        if (j < MTOT) s_C[j] = prefix + loc[c];
    }
    __syncthreads();

    // ---- rectangular smoothing + log ----
    float width = f0 * (2.0f / 3.0f);
    float wbins = width * (2048.0f / 24000.0f);
#pragma unroll
    for (int c5 = 0; c5 < 5; ++c5) {
        int k = tid + (c5 << 8);
        if (k < K1) {
            float pos_lo = (float)k - 0.5f * wbins + ((float)KPAD - 0.5f);
            float pos_hi = pos_lo + wbins;
            int llo = (int)floorf(pos_lo); llo = max(0, min(MTOT - 2, llo));
            float flo = pos_lo - (float)llo;
            float clo = s_C[llo] + (s_C[llo + 1] - s_C[llo]) * flo;
            int lhi = (int)floorf(pos_hi); lhi = max(0, min(MTOT - 2, lhi));
            float fhi = pos_hi - (float)lhi;
            float chi = s_C[lhi] + (s_C[lhi + 1] - s_C[lhi]) * fhi;
            s_P[k] = __logf((chi - clo) / width);
        }
    }
    __syncthreads();

    // ---- FFT2: pack even extension of logP ----
#pragma unroll
    for (int c = 0; c < 4; ++c) {
        int m = tid + (c << 8);
        int j0 = 2 * m;
        int j1 = 2 * m + 1;
        float v0 = (j0 <= N1) ? s_P[j0] : s_P[NFFT - j0];
        float v1 = (j1 <= N1) ? s_P[j1] : s_P[NFFT - j1];
        s_c[A(m)] = make_float2(v0, v1);
    }
    __syncthreads();
    fft1024(s_c, tid, tw);

    // ---- unpack + lifter -> s_P ; cl via cos(2a)=1-2sin^2(a) ----
#pragma unroll
    for (int c5 = 0; c5 < 5; ++c5) {
        int k = tid + (c5 << 8);
        if (k < K1) {
            cpx X = unpack_k(s_c, k, cmul(u2048, W8[c5]));
            float cep = X.x * (1.0f / 2048.0f);
            float pz = PIF * f0 * ((float)k * (1.0f / 24000.0f));
            float s = __sinf(pz);
            float sl = (k != 0) ? (s / pz) : 1.0f;
            float cl = 1.0f + 0.6f * s * s;
            s_P[k] = cep * sl * cl;
        }
    }
    __syncthreads();

    // ---- FFT3: pack even extension of lifted cepstrum ----
#pragma unroll
    for (int c = 0; c < 4; ++c) {
        int m = tid + (c << 8);
        int j0 = 2 * m;
        int j1 = 2 * m + 1;
        float v0 = (j0 <= N1) ? s_P[j0] : s_P[NFFT - j0];
        float v1 = (j1 <= N1) ? s_P[j1] : s_P[NFFT - j1];
        s_c[A(m)] = make_float2(v0, v1);
    }
    __syncthreads();
    fft1024(s_c, tid, tw);

    // ---- unpack + store ----
    float* orow = out + (size_t)(b * NFRAMES + n) * K1;
#pragma unroll
    for (int c5 = 0; c5 < 5; ++c5) {
        int k = tid + (c5 << 8);
        if (k < K1) {
            cpx X = unpack_k(s_c, k, cmul(u2048, W8[c5]));
            orow[k] = X.x;
        }
    }
}

extern "C" void kernel_launch(void* const* d_in, const int* in_sizes, int n_in,
                              void* d_out, int out_size, void* d_ws, size_t ws_size,
                              hipStream_t stream) {
    (void)in_sizes; (void)n_in; (void)d_ws; (void)ws_size; (void)out_size;
    const float* x  = (const float*)d_in[0];
    const float* f0 = (const float*)d_in[1];
    float* out = (float*)d_out;
    dim3 grid(NFRAMES, BATCH);
    hipLaunchKernelGGL(cheaptrick_kernel, grid, dim3(256), 0, stream, x, f0, out);
}

// Round 7
// 161.455 us; speedup vs baseline: 1.2655x; 1.2655x over previous
//
#include <hip/hip_runtime.h>
#include <math.h>

#define NFFT   2048
#define N1     1024
#define K1     1025
#define KPAD   36
#define MTOT   1097   // K1 + 2*KPAD
#define NFRAMES 1001
#define TLEN   120000
#define BATCH  8
#define FPER   120
#define PIF 3.14159265358979323846f

// LDS swizzle for 8B (float2) elements; balanced for all radix-4 strides and
// the stride-16 brev gathers. Remaining SQ_LDS_BANK_CONFLICT (~1.4e7) is the
// intrinsic multi-cycle cost of 512B/wave b64 ops, not misalignment.
#define A(i) ((i) + ((i) >> 4))      // max 1023 -> 1086; array sized 1088

typedef float2 cpx;
__device__ __forceinline__ cpx cmul(cpx a, cpx b) {
    return make_float2(a.x * b.x - a.y * b.y, a.x * b.y + a.y * b.x);
}
__device__ __forceinline__ cpx cadd(cpx a, cpx b) { return make_float2(a.x + b.x, a.y + b.y); }
__device__ __forceinline__ cpx csub(cpx a, cpx b) { return make_float2(a.x - b.x, a.y - b.y); }

__device__ __forceinline__ int brev10(int v) {
    return (int)(__brev((unsigned)v) >> 22);
}

// ---- fused radix-4 DIF stage (spans H and H/2); w1 = W_{2H}^{tid&(H/2-1)} ----
template<int H>
__device__ __forceinline__ void dif_fused(cpx* c, int tid, cpx w1) {
    int r  = tid & (H / 2 - 1);
    int i0 = (tid / (H / 2)) * (2 * H) + r;
    int ia = A(i0), ib = A(i0 + H / 2), ic = A(i0 + H), id = A(i0 + 3 * H / 2);
    cpx a = c[ia], b = c[ib], cc = c[ic], d = c[id];
    cpx w1n = make_float2(w1.y, -w1.x);                       // -i*w1
    cpx w2  = make_float2(w1.x * w1.x - w1.y * w1.y, 2.0f * w1.x * w1.y);
    cpx a1 = cadd(a, cc);
    cpx c1 = cmul(csub(a, cc), w1);
    cpx b1 = cadd(b, d);
    cpx d1 = cmul(csub(b, d), w1n);
    c[ia] = cadd(a1, b1);
    c[ib] = cmul(csub(a1, b1), w2);
    c[ic] = cadd(c1, d1);
    c[id] = cmul(csub(c1, d1), w2);
    __syncthreads();
}

// last stage (H=2): twiddles are 1 and -i — no multiplies.
__device__ __forceinline__ void dif_last2(cpx* c, int tid) {
    int i0 = 4 * tid;
    int ia = A(i0), ib = A(i0 + 1), ic = A(i0 + 2), id = A(i0 + 3);
    cpx a = c[ia], b = c[ib], cc = c[ic], d = c[id];
    cpx a1 = cadd(a, cc);
    cpx c1 = csub(a, cc);
    cpx b1 = cadd(b, d);
    cpx bd = csub(b, d);
    cpx d1 = make_float2(bd.y, -bd.x);                        // -i*(b-d)
    c[ia] = cadd(a1, b1);
    c[ib] = csub(a1, b1);
    c[ic] = cadd(c1, d1);
    c[id] = csub(c1, d1);
    __syncthreads();
}

__device__ __forceinline__ void fft1024(cpx* c, int tid, const cpx* tw) {
    dif_fused<512>(c, tid, tw[0]);
    dif_fused<128>(c, tid, tw[1]);
    dif_fused<32>(c, tid, tw[2]);
    dif_fused<8>(c, tid, tw[3]);
    dif_last2(c, tid);
}

// Unpack: X[k] = E + w*O, w = W_2048^k (precomputed by caller).
__device__ __forceinline__ cpx unpack_k(const cpx* s_c, int k, cpx w) {
    int kk = k & (N1 - 1);
    int mm = (N1 - kk) & (N1 - 1);
    cpx Zk = s_c[A(brev10(kk))];
    cpx Zm = s_c[A(brev10(mm))];
    float Ex = 0.5f * (Zk.x + Zm.x), Ey = 0.5f * (Zk.y - Zm.y);
    float Ox = 0.5f * (Zk.y + Zm.y), Oy = 0.5f * (Zm.x - Zk.x);
    return make_float2(Ex + w.x * Ox - w.y * Oy,
                       Ey + w.x * Oy + w.y * Ox);
}

// NO min-waves arg: on this toolchain __launch_bounds__(256,w) caps VGPRs at
// 256/w AND residency at w blocks/CU. w=4 pinned occupancy to 40% (r5);
// w>=5 forced spills (r2: 48 VGPR cap / r4: 40 / r6: 32 -> 600 MB scratch
// traffic). Uncapped, the kernel needs ~52-76 VGPR -> HW allows 6-8 blocks/CU
// (LDS 17.4 KB allows 9). Spill canary: WRITE_SIZE must stay ~32.3 MB.
__global__ __launch_bounds__(256)
void cheaptrick_kernel(const float* __restrict__ x,
                       const float* __restrict__ f0in,
                       float* __restrict__ out) {
    __shared__ cpx   s_c[1088];
    __shared__ float s_P[1026];
    __shared__ float s_C[MTOT];
    __shared__ float s_scan[16];

    const int tid  = threadIdx.x;
    const int lane = tid & 63;
    const int wid  = tid >> 6;
    const int n    = blockIdx.x;
    const int b    = blockIdx.y;

    float f0 = f0in[b * NFRAMES + n];
    const float F_MIN = 72000.0f / 2045.0f;
    if (f0 <= F_MIN) f0 = 500.0f;

    // ---- frame extraction + raw window (thread-contiguous l = 8t+j) ----
    float fr[8], wn[8];
    float hwl = rintf(36000.0f / f0);
    float s_w2 = 0.0f, s_w = 0.0f, s_fw = 0.0f;
    int base_idx = n * FPER - N1 + 8 * tid;
#pragma unroll
    for (int j = 0; j < 8; ++j) {
        int l = 8 * tid + j;
        float relf = (float)(l - N1);
        int idx = max(0, min(TLEN - 1, base_idx + j));
        fr[j] = x[b * TLEN + idx];
        float w = 0.0f;
        if (fabsf(relf) <= hwl) {
            w = 0.5f * __cosf(PIF * relf / 36000.0f * f0) + 0.5f;
        }
        wn[j] = w;
        s_w2 += w * w;
        s_w  += w;
        s_fw += fr[j] * w;
    }
#pragma unroll
    for (int off = 32; off > 0; off >>= 1) {
        s_w2 += __shfl_down(s_w2, off, 64);
        s_w  += __shfl_down(s_w,  off, 64);
        s_fw += __shfl_down(s_fw, off, 64);
    }
    if (lane == 0) {
        s_scan[wid]     = s_w2;
        s_scan[4 + wid] = s_w;
        s_scan[8 + wid] = s_fw;
    }
    __syncthreads();
    float w2sum = s_scan[0] + s_scan[1] + s_scan[2] + s_scan[3];
    float wsum  = s_scan[4] + s_scan[5] + s_scan[6] + s_scan[7];
    float fwsum = s_scan[8] + s_scan[9] + s_scan[10] + s_scan[11];
    float wscale = 1.0f / sqrtf(w2sum);
    float dc = fwsum / wsum;
    __syncthreads();          // s_scan reuse below

    // ---- FFT1 pack (register-local): z[m] = w[2m] + i*w[2m+1] ----
#pragma unroll
    for (int j = 0; j < 4; ++j) {
        float v0 = wscale * wn[2 * j]     * (fr[2 * j]     - dc);
        float v1 = wscale * wn[2 * j + 1] * (fr[2 * j + 1] - dc);
        s_c[A(4 * tid + j)] = make_float2(v0, v1);
    }

    // ---- twiddle caches (fr/wn now dead; computed once, reused by 3 FFTs) ----
    cpx tw[4], u2048;
    {
        float sn, cs;
        __sincosf(-PIF * (float)(tid & 255) * (1.0f / 512.0f), &sn, &cs);
        tw[0] = make_float2(cs, sn);
        __sincosf(-PIF * (float)(tid & 63) * (1.0f / 128.0f), &sn, &cs);
        tw[1] = make_float2(cs, sn);
        __sincosf(-PIF * (float)(tid & 15) * (1.0f / 32.0f), &sn, &cs);
        tw[2] = make_float2(cs, sn);
        __sincosf(-PIF * (float)(tid & 3) * (1.0f / 8.0f), &sn, &cs);
        tw[3] = make_float2(cs, sn);
        __sincosf(-PIF * (float)tid * (1.0f / 1024.0f), &sn, &cs);
        u2048 = make_float2(cs, sn);          // W_2048^tid
    }
    const float RH = 0.70710678118654752f;
    const cpx W8[5] = { make_float2(1.0f, 0.0f), make_float2(RH, -RH),
                        make_float2(0.0f, -1.0f), make_float2(-RH, -RH),
                        make_float2(-1.0f, 0.0f) };           // W_2048^(256c)

    __syncthreads();
    fft1024(s_c, tid, tw);

    // ---- unpack + power spectrum ----
#pragma unroll
    for (int c5 = 0; c5 < 5; ++c5) {
        int k = tid + (c5 << 8);
        if (k < K1) {
            cpx X = unpack_k(s_c, k, cmul(u2048, W8[c5]));
            s_P[k] = X.x * X.x + X.y * X.y;
        }
    }
    __syncthreads();

    // ---- sub-f0 replacement ----
    float rate = f0 * (2048.0f / 24000.0f);
    int kmax = (int)floorf(rate);
    float repl = 0.0f;
    if (tid <= kmax) {
        float m = rate - (float)tid;
        int lo = (int)floorf(m);
        lo = max(0, min(K1 - 2, lo));
        float frac = m - (float)lo;
        repl = s_P[lo] * (1.0f - frac) + s_P[lo + 1] * frac;
    }
    __syncthreads();
    if (tid <= kmax) s_P[tid] += repl;
    __syncthreads();

    // ---- reflected cumsum: serial-5 + wave shuffle scan ----
    float loc[5];
    float run = 0.0f;
    int basej = tid * 5;
#pragma unroll
    for (int c = 0; c < 5; ++c) {
        int j = basej + c;
        float v = 0.0f;
        if (j < MTOT) {
            int a = abs(j - KPAD);
            if (a > N1) a = NFFT - a;
            v = s_P[a] * (24000.0f / 2048.0f);
        }
        run += v;
        loc[c] = run;
    }
    float v = run;
#pragma unroll
    for (int off = 1; off < 64; off <<= 1) {
        float o = __shfl_up(v, off, 64);
        if (lane >= off) v += o;
    }
    if (lane == 63) s_scan[wid] = v;
    __syncthreads();
    float wbase = 0.0f;
#pragma unroll
    for (int w = 0; w < 4; ++w) wbase += (w < wid) ? s_scan[w] : 0.0f;
    float prefix = wbase + v - run;
#pragma unroll
    for (int c = 0; c < 5; ++c) {
        int j = basej + c;
        if (j < MTOT) s_C[j] = prefix + loc[c];
    }
    __syncthreads();

    // ---- rectangular smoothing + log ----
    float width = f0 * (2.0f / 3.0f);
    float wbins = width * (2048.0f / 24000.0f);
#pragma unroll
    for (int c5 = 0; c5 < 5; ++c5) {
        int k = tid + (c5 << 8);
        if (k < K1) {
            float pos_lo = (float)k - 0.5f * wbins + ((float)KPAD - 0.5f);
            float pos_hi = pos_lo + wbins;
            int llo = (int)floorf(pos_lo); llo = max(0, min(MTOT - 2, llo));
            float flo = pos_lo - (float)llo;
            float clo = s_C[llo] + (s_C[llo + 1] - s_C[llo]) * flo;
            int lhi = (int)floorf(pos_hi); lhi = max(0, min(MTOT - 2, lhi));
            float fhi = pos_hi - (float)lhi;
            float chi = s_C[lhi] + (s_C[lhi + 1] - s_C[lhi]) * fhi;
            s_P[k] = __logf((chi - clo) / width);
        }
    }
    __syncthreads();

    // ---- FFT2: pack even extension of logP ----
#pragma unroll
    for (int c = 0; c < 4; ++c) {
        int m = tid + (c << 8);
        int j0 = 2 * m;
        int j1 = 2 * m + 1;
        float v0 = (j0 <= N1) ? s_P[j0] : s_P[NFFT - j0];
        float v1 = (j1 <= N1) ? s_P[j1] : s_P[NFFT - j1];
        s_c[A(m)] = make_float2(v0, v1);
    }
    __syncthreads();
    fft1024(s_c, tid, tw);

    // ---- unpack + lifter -> s_P ; cl via cos(2a)=1-2sin^2(a) ----
#pragma unroll
    for (int c5 = 0; c5 < 5; ++c5) {
        int k = tid + (c5 << 8);
        if (k < K1) {
            cpx X = unpack_k(s_c, k, cmul(u2048, W8[c5]));
            float cep = X.x * (1.0f / 2048.0f);
            float pz = PIF * f0 * ((float)k * (1.0f / 24000.0f));
            float s = __sinf(pz);
            float sl = (k != 0) ? (s / pz) : 1.0f;
            float cl = 1.0f + 0.6f * s * s;
            s_P[k] = cep * sl * cl;
        }
    }
    __syncthreads();

    // ---- FFT3: pack even extension of lifted cepstrum ----
#pragma unroll
    for (int c = 0; c < 4; ++c) {
        int m = tid + (c << 8);
        int j0 = 2 * m;
        int j1 = 2 * m + 1;
        float v0 = (j0 <= N1) ? s_P[j0] : s_P[NFFT - j0];
        float v1 = (j1 <= N1) ? s_P[j1] : s_P[NFFT - j1];
        s_c[A(m)] = make_float2(v0, v1);
    }
    __syncthreads();
    fft1024(s_c, tid, tw);

    // ---- unpack + store ----
    float* orow = out + (size_t)(b * NFRAMES + n) * K1;
#pragma unroll
    for (int c5 = 0; c5 < 5; ++c5) {
        int k = tid + (c5 << 8);
        if (k < K1) {
            cpx X = unpack_k(s_c, k, cmul(u2048, W8[c5]));
            orow[k] = X.x;
        }
    }
}

extern "C" void kernel_launch(void* const* d_in, const int* in_sizes, int n_in,
                              void* d_out, int out_size, void* d_ws, size_t ws_size,
                              hipStream_t stream) {
    (void)in_sizes; (void)n_in; (void)d_ws; (void)ws_size; (void)out_size;
    const float* x  = (const float*)d_in[0];
    const float* f0 = (const float*)d_in[1];
    float* out = (float*)d_out;
    dim3 grid(NFRAMES, BATCH);
    hipLaunchKernelGGL(cheaptrick_kernel, grid, dim3(256), 0, stream, x, f0, out);
}